// Round 4
// baseline (567.812 us; speedup 1.0000x reference)
//
#include <hip/hip_runtime.h>
#include <math.h>

#define NNODES 50000
#define NEDGES 800000
#define KIN 1024
#define DH 128

typedef __bf16 bf16x8 __attribute__((ext_vector_type(8)));
typedef float floatx4 __attribute__((ext_vector_type(4)));

// ---------------- CSR build ----------------
__global__ void k_zero2(int* __restrict__ a, int* __restrict__ b, int n) {
  int i = blockIdx.x * blockDim.x + threadIdx.x;
  if (i < n) { a[i] = 0; b[i] = 0; }
}

__global__ void k_hist(const int* __restrict__ dst, int* __restrict__ cnt, int E) {
  int i = blockIdx.x * blockDim.x + threadIdx.x;
  if (i < E) atomicAdd(&cnt[dst[i]], 1);
}

__global__ __launch_bounds__(1024) void k_scan_local(const int* __restrict__ cnt,
                                                     int* __restrict__ row_ptr,
                                                     int* __restrict__ bsum, int n) {
  __shared__ int sd[1024];
  int t = threadIdx.x;
  int i = blockIdx.x * 1024 + t;
  int v = (i < n) ? cnt[i] : 0;
  sd[t] = v;
  __syncthreads();
  for (int off = 1; off < 1024; off <<= 1) {
    int tv = (t >= off) ? sd[t - off] : 0;
    __syncthreads();
    sd[t] += tv;
    __syncthreads();
  }
  if (i < n) row_ptr[i] = sd[t] - v;
  if (t == 1023) bsum[blockIdx.x] = sd[t];
}

__global__ void k_scan_sums(const int* __restrict__ bsum, int* __restrict__ boff,
                            int nb, int* __restrict__ row_ptr, int n) {
  int lane = threadIdx.x;  // 64 threads
  int v = (lane < nb) ? bsum[lane] : 0;
  int incl = v;
  for (int off = 1; off < 64; off <<= 1) {
    int t = __shfl_up(incl, off);
    if (lane >= off) incl += t;
  }
  boff[lane] = incl - v;
  if (lane == 63) row_ptr[n] = incl;
}

__global__ void k_scan_add(int* __restrict__ row_ptr, const int* __restrict__ boff, int n) {
  int i = blockIdx.x * blockDim.x + threadIdx.x;
  if (i < n) row_ptr[i] += boff[i >> 10];
}

__global__ void k_fill(const int* __restrict__ src, const int* __restrict__ dst,
                       const int* __restrict__ row_ptr, int* __restrict__ cursor,
                       int* __restrict__ csr_src, int E) {
  int i = blockIdx.x * blockDim.x + threadIdx.x;
  if (i < E) {
    int d = dst[i];
    int pos = row_ptr[d] + atomicAdd(&cursor[d], 1);
    csr_src[pos] = src[i];
  }
}

// ---------------- B prepack into MFMA-fragment order ----------------
// Bf chunk id = ((kb*16 + nt)*2 + ks)*64 + lane, 8 bf16 (16 B) each:
// elem j = Wcat[kb*64 + ks*32 + (lane>>4)*8 + j][nt*16 + (lane&15)]
__global__ __launch_bounds__(256) void k_prepF(const float* __restrict__ W,
                                               const float* __restrict__ Wr,
                                               __bf16* __restrict__ Bf) {
  const int id = blockIdx.x * 256 + threadIdx.x;
  const int lane = id & 63;
  const int ks = (id >> 6) & 1;
  const int nt = (id >> 7) & 15;
  const int kb = id >> 11;
  const int n = nt * 16 + (lane & 15);
  const int k0 = kb * 64 + ks * 32 + (lane >> 4) * 8;
  bf16x8 h;
#pragma unroll
  for (int j = 0; j < 8; ++j) {
    const int k = k0 + j;
    const float v = (n < DH) ? W[(size_t)k * DH + n] : Wr[(size_t)k * DH + (n - DH)];
    h[j] = (__bf16)v;
  }
  *(bf16x8*)&Bf[(size_t)id * 8] = h;
}

// ---------------- barrier-free MFMA GEMM ----------------
// BM=32 x N=256 (cols 0..127 -> XW bf16, 128..255 -> RES f32), 256 thr = 4 waves.
// A staged ONCE into LDS (32 x K bf16, 16B chunks XOR-swizzled by row&7);
// single barrier; K-loop reads A frags from LDS + B frags from fragment-packed
// global (L2-resident) with plain coalesced dwordx4 — no barriers, no vmcnt(0)
// drain; compiler pipelines loads across the unroll-2 body.
template <typename AT, int K>
__global__ __launch_bounds__(256) void k_gemm3(
    const AT* __restrict__ X, const __bf16* __restrict__ Bf,
    const float* __restrict__ br, __bf16* __restrict__ XW,
    float* __restrict__ RES, int M) {
  constexpr unsigned ABYTES = 32u * K * 2u;
  constexpr unsigned SMEM = (ABYTES > 32768u) ? ABYTES : 32768u;  // epilogue needs 32KB
  __shared__ alignas(16) char smem[SMEM];
  __bf16* As = (__bf16*)smem;  // [32][K], chunk c stored at slot c^(row&7) (within groups of 8)
  const int tid = threadIdx.x;
  const int lane = tid & 63;
  const int w = tid >> 6;
  const int l15 = lane & 15;
  const int quad = lane >> 4;
  const int bm0 = blockIdx.x * 32;

  // ---- stage A once: thread -> row tid>>3, chunks (tid&7)+8j ----
  {
    const int row = tid >> 3;
    int grow = bm0 + row;
    if (grow > M - 1) grow = M - 1;
    const AT* ap = X + (size_t)grow * K;
#pragma unroll 4
    for (int j = 0; j < K / 64; ++j) {
      const int c = (tid & 7) + 8 * j;  // 16B chunk index 0..K/8-1
      bf16x8 h;
      if constexpr (sizeof(AT) == 4) {
        const float4 u = *(const float4*)(ap + c * 8);
        const float4 v = *(const float4*)(ap + c * 8 + 4);
        h[0] = (__bf16)u.x; h[1] = (__bf16)u.y; h[2] = (__bf16)u.z; h[3] = (__bf16)u.w;
        h[4] = (__bf16)v.x; h[5] = (__bf16)v.y; h[6] = (__bf16)v.z; h[7] = (__bf16)v.w;
      } else {
        h = *(const bf16x8*)(ap + c * 8);
      }
      const int cs = (c & ~7) | ((c ^ row) & 7);  // XOR swizzle within 8-chunk group
      *(bf16x8*)&As[(size_t)row * K + (cs << 3)] = h;
    }
  }
  __syncthreads();

  floatx4 acc[2][4];
#pragma unroll
  for (int i = 0; i < 2; ++i)
#pragma unroll
    for (int j = 0; j < 4; ++j) acc[i][j] = (floatx4)0.f;

#pragma unroll 2
  for (int kb = 0; kb < K / 64; ++kb) {
    bf16x8 bfr[4][2];
#pragma unroll
    for (int nt = 0; nt < 4; ++nt)
#pragma unroll
      for (int ks = 0; ks < 2; ++ks) {
        const int ntg = (w << 2) + nt;  // global n-tile 0..15
        const size_t idx = ((((size_t)kb * 16 + ntg) * 2 + ks) * 64 + lane) * 8;
        bfr[nt][ks] = *(const bf16x8*)(Bf + idx);
      }
    bf16x8 af[2][2];
#pragma unroll
    for (int mt = 0; mt < 2; ++mt)
#pragma unroll
      for (int ks = 0; ks < 2; ++ks) {
        const int row = mt * 16 + l15;
        const int c = kb * 8 + ks * 4 + quad;
        const int cs = (c & ~7) | ((c ^ row) & 7);
        af[mt][ks] = *(const bf16x8*)&As[(size_t)row * K + (cs << 3)];
      }
#pragma unroll
    for (int ks = 0; ks < 2; ++ks)
#pragma unroll
      for (int mt = 0; mt < 2; ++mt)
#pragma unroll
        for (int nt = 0; nt < 4; ++nt)
          acc[mt][nt] = __builtin_amdgcn_mfma_f32_16x16x32_bf16(af[mt][ks], bfr[nt][ks],
                                                                acc[mt][nt], 0, 0, 0);
  }

  // ---- epilogue via LDS transpose (smem reused as f32 Cb[32][256]) ----
  __syncthreads();
  float* Cb = (float*)smem;
#pragma unroll
  for (int mt = 0; mt < 2; ++mt)
#pragma unroll
    for (int nt = 0; nt < 4; ++nt)
#pragma unroll
      for (int r = 0; r < 4; ++r)
        Cb[(mt * 16 + quad * 4 + r) * 256 + ((w << 6) + nt * 16 + l15)] = acc[mt][nt][r];
  __syncthreads();
  const int row = tid >> 3;
  const int seg = tid & 7;
  const int grow = bm0 + row;
  if (grow < M) {
    if (seg < 4) {  // XW cols seg*32..+31 -> bf16
      const int c0 = seg * 32;
#pragma unroll
      for (int j = 0; j < 4; ++j) {
        const float4 v0 = *(const float4*)&Cb[row * 256 + c0 + j * 8];
        const float4 v1 = *(const float4*)&Cb[row * 256 + c0 + j * 8 + 4];
        bf16x8 h;
        h[0] = (__bf16)v0.x; h[1] = (__bf16)v0.y; h[2] = (__bf16)v0.z; h[3] = (__bf16)v0.w;
        h[4] = (__bf16)v1.x; h[5] = (__bf16)v1.y; h[6] = (__bf16)v1.z; h[7] = (__bf16)v1.w;
        *(bf16x8*)&XW[(size_t)grow * DH + c0 + j * 8] = h;
      }
    } else {  // RES cols (seg-4)*32..+31 -> relu(x+br) f32
      const int c0 = (seg - 4) * 32;
#pragma unroll
      for (int j = 0; j < 8; ++j) {
        const float4 v = *(const float4*)&Cb[row * 256 + 128 + c0 + j * 4];
        const float4 bb = *(const float4*)&br[c0 + j * 4];
        *(float4*)&RES[(size_t)grow * DH + c0 + j * 4] =
            make_float4(fmaxf(v.x + bb.x, 0.f), fmaxf(v.y + bb.y, 0.f),
                        fmaxf(v.z + bb.z, 0.f), fmaxf(v.w + bb.w, 0.f));
      }
    }
  }
}

// ---------------- aggregation + bias + relu + residual + BN (+ fused head) ----------------
template <int MODE>
__global__ __launch_bounds__(256) void k_agg2(
    const __bf16* __restrict__ XW, const float* __restrict__ RES,
    const int* __restrict__ row_ptr, const int* __restrict__ csr_src,
    const float* __restrict__ b, const float* __restrict__ gamma,
    const float* __restrict__ beta, const float* __restrict__ mean,
    const float* __restrict__ var, const float* __restrict__ Wd,
    const float* __restrict__ bd, void* __restrict__ hout, int M) {
  const int node = (blockIdx.x << 2) + (threadIdx.x >> 6);
  const int lane = threadIdx.x & 63;
  if (node >= M) return;
  const int s = row_ptr[node], e = row_ptr[node + 1];
  const unsigned* xw = (const unsigned*)XW;
  float ax = 0.f, ay = 0.f;
  int i = s;
  for (; i + 3 < e; i += 4) {
    const int s0 = csr_src[i], s1 = csr_src[i + 1], s2 = csr_src[i + 2], s3 = csr_src[i + 3];
    const unsigned u0 = xw[(size_t)s0 * 64 + lane];
    const unsigned u1 = xw[(size_t)s1 * 64 + lane];
    const unsigned u2 = xw[(size_t)s2 * 64 + lane];
    const unsigned u3 = xw[(size_t)s3 * 64 + lane];
    ax += __uint_as_float(u0 << 16) + __uint_as_float(u1 << 16) +
          __uint_as_float(u2 << 16) + __uint_as_float(u3 << 16);
    ay += __uint_as_float(u0 & 0xffff0000u) + __uint_as_float(u1 & 0xffff0000u) +
          __uint_as_float(u2 & 0xffff0000u) + __uint_as_float(u3 & 0xffff0000u);
  }
  for (; i < e; ++i) {
    const unsigned u = xw[(size_t)csr_src[i] * 64 + lane];
    ax += __uint_as_float(u << 16);
    ay += __uint_as_float(u & 0xffff0000u);
  }
  const int f0 = lane << 1;
  const float2 bb = *(const float2*)&b[f0];
  const float2 rr = *(const float2*)&RES[(size_t)node * DH + f0];
  const float2 mm = *(const float2*)&mean[f0];
  const float2 vv = *(const float2*)&var[f0];
  const float2 gg = *(const float2*)&gamma[f0];
  const float2 be = *(const float2*)&beta[f0];
  const float x0 = fmaxf(ax + bb.x, 0.f) + rr.x;
  const float x1 = fmaxf(ay + bb.y, 0.f) + rr.y;
  const float y0 = (x0 - mm.x) * rsqrtf(vv.x + 1e-5f) * gg.x + be.x;
  const float y1 = (x1 - mm.y) * rsqrtf(vv.y + 1e-5f) * gg.y + be.y;
  if (MODE == 0) {
    union { __bf16 h[2]; unsigned u; } pk;
    pk.h[0] = (__bf16)y0;
    pk.h[1] = (__bf16)y1;
    ((unsigned*)hout)[(size_t)node * 64 + lane] = pk.u;
  } else {
    const float4 wv = *(const float4*)&Wd[f0 * 2];
    float l0 = y0 * wv.x + y1 * wv.z;
    float l1 = y0 * wv.y + y1 * wv.w;
#pragma unroll
    for (int off = 32; off > 0; off >>= 1) {
      l0 += __shfl_down(l0, off);
      l1 += __shfl_down(l1, off);
    }
    if (lane == 0) {
      l0 += bd[0];
      l1 += bd[1];
      const float m = fmaxf(l0, l1);
      const float e0 = expf(l0 - m), e1 = expf(l1 - m);
      const float inv = 1.f / (e0 + e1);
      float* out = (float*)hout;
      out[(size_t)node * 2] = e0 * inv;
      out[(size_t)node * 2 + 1] = e1 * inv;
    }
  }
}

// ---------------- launch ----------------
extern "C" void kernel_launch(void* const* d_in, const int* in_sizes, int n_in,
                              void* d_out, int out_size, void* d_ws, size_t ws_size,
                              hipStream_t stream) {
  const float* in_feat = (const float*)d_in[0];
  const int* src = (const int*)d_in[1];
  const int* dst = (const int*)d_in[2];
  const float* W0 = (const float*)d_in[3];
  const float* b0 = (const float*)d_in[4];
  const float* Wr0 = (const float*)d_in[5];
  const float* br0 = (const float*)d_in[6];
  const float* gamma0 = (const float*)d_in[7];
  const float* beta0 = (const float*)d_in[8];
  const float* mean0 = (const float*)d_in[9];
  const float* var0 = (const float*)d_in[10];
  const float* W1 = (const float*)d_in[11];
  const float* b1 = (const float*)d_in[12];
  const float* Wr1 = (const float*)d_in[13];
  const float* br1 = (const float*)d_in[14];
  const float* gamma1 = (const float*)d_in[15];
  const float* beta1 = (const float*)d_in[16];
  const float* mean1 = (const float*)d_in[17];
  const float* var1 = (const float*)d_in[18];
  const float* Wd = (const float*)d_in[19];
  const float* bd = (const float*)d_in[20];
  float* out = (float*)d_out;

  char* ws = (char*)d_ws;
  size_t off = 0;
  auto alloc = [&](size_t bytes) {
    void* p = ws + off;
    off += (bytes + 255) & ~(size_t)255;
    return p;
  };
  __bf16* XWb = (__bf16*)alloc(sizeof(__bf16) * (size_t)NNODES * DH);
  __bf16* h1 = (__bf16*)alloc(sizeof(__bf16) * (size_t)NNODES * DH);
  float* RES = (float*)alloc(sizeof(float) * (size_t)NNODES * DH);
  int* cnt = (int*)alloc(sizeof(int) * NNODES);
  int* cursor = (int*)alloc(sizeof(int) * NNODES);
  int* row_ptr = (int*)alloc(sizeof(int) * (NNODES + 1));
  int* csr_src = (int*)alloc(sizeof(int) * NEDGES);
  int* bsum = (int*)alloc(sizeof(int) * 64);
  int* boff = (int*)alloc(sizeof(int) * 64);
  __bf16* Bf0 = (__bf16*)alloc(sizeof(__bf16) * 256 * KIN);  // fragment-packed
  __bf16* Bf1 = (__bf16*)alloc(sizeof(__bf16) * 256 * DH);

  const int nb = (NNODES + 1023) / 1024;  // 49
  // CSR build
  k_zero2<<<(NNODES + 255) / 256, 256, 0, stream>>>(cnt, cursor, NNODES);
  k_hist<<<(NEDGES + 255) / 256, 256, 0, stream>>>(dst, cnt, NEDGES);
  k_scan_local<<<nb, 1024, 0, stream>>>(cnt, row_ptr, bsum, NNODES);
  k_scan_sums<<<1, 64, 0, stream>>>(bsum, boff, nb, row_ptr, NNODES);
  k_scan_add<<<(NNODES + 255) / 256, 256, 0, stream>>>(row_ptr, boff, NNODES);
  k_fill<<<(NEDGES + 255) / 256, 256, 0, stream>>>(src, dst, row_ptr, cursor, csr_src, NEDGES);

  // weight prepack (fragment order): K=1024 -> 32768 chunks, K=128 -> 4096
  k_prepF<<<(KIN / 64) * 16 * 2 * 64 / 256, 256, 0, stream>>>(W0, Wr0, Bf0);
  k_prepF<<<(DH / 64) * 16 * 2 * 64 / 256, 256, 0, stream>>>(W1, Wr1, Bf1);

  const int ggrid = (NNODES + 31) / 32;
  const int agrid = (NNODES + 3) / 4;
  // layer 0
  k_gemm3<float, KIN><<<ggrid, 256, 0, stream>>>(in_feat, Bf0, br0, XWb, RES, NNODES);
  k_agg2<0><<<agrid, 256, 0, stream>>>(XWb, RES, row_ptr, csr_src, b0, gamma0, beta0,
                                       mean0, var0, nullptr, nullptr, h1, NNODES);
  // layer 1 (+ fused head)
  k_gemm3<__bf16, DH><<<ggrid, 256, 0, stream>>>(h1, Bf1, br1, XWb, RES, NNODES);
  k_agg2<1><<<agrid, 256, 0, stream>>>(XWb, RES, row_ptr, csr_src, b1, gamma1, beta1,
                                       mean1, var1, Wd, bd, out, NNODES);
}